// Round 14
// baseline (243.588 us; speedup 1.0000x reference)
//
#include <hip/hip_runtime.h>
#include <math.h>

// Problem constants: B=32, C=64, H=128, W=128
#define HW 16384         // plane elements
#define NPLANE 2048      // B*C planes
#define SLOTB 65536ull   // bytes per plane slot in d_out (fp32 plane)

typedef __fp16 f16x2 __attribute__((ext_vector_type(2)));
typedef __bf16 bf16x8 __attribute__((ext_vector_type(8)));
typedef float  f32x4  __attribute__((ext_vector_type(4)));

__device__ __forceinline__ unsigned pk16(float a, float b) {
    f16x2 h = __builtin_amdgcn_cvt_pkrtz(a, b);
    return __builtin_bit_cast(unsigned, h);
}
__device__ __forceinline__ float2 up16(unsigned u) {
    f16x2 h = __builtin_bit_cast(f16x2, u);
    return make_float2((float)h[0], (float)h[1]);
}
__device__ __forceinline__ float bf2f(unsigned short s) {
    unsigned u = (unsigned)s << 16;
    return __builtin_bit_cast(float, u);
}
__device__ __forceinline__ unsigned short f2bf(float f) {
    __bf16 h = (__bf16)f;
    return __builtin_bit_cast(unsigned short, h);
}

__device__ __forceinline__ void bf_quad(float4& a) {
    float s0 = a.x + a.y, d0 = a.x - a.y;
    float s1 = a.z + a.w, d1 = a.z - a.w;
    a.x = s0 + s1; a.y = d0 + d1; a.z = s0 - s1; a.w = d0 - d1;
}
__device__ __forceinline__ void bf_pair(float4& a, float4& b) {
    float4 s, d;
    s.x = a.x + b.x; s.y = a.y + b.y; s.z = a.z + b.z; s.w = a.w + b.w;
    d.x = a.x - b.x; d.y = a.y - b.y; d.z = a.z - b.z; d.w = a.w - b.w;
    a = s; b = d;
}

// ---------------------------------------------------------------------------
// 14-stage WHT over one 16384 plane. 256 threads x 64 elems. (verified R8)
// ---------------------------------------------------------------------------
__device__ __forceinline__ void wht_ABC(float4 (&r)[16], unsigned* lds, int t,
                                        float4 (&c)[16]) {
    const int t0 = t & 1, t1 = (t >> 1) & 1, t2 = (t >> 2) & 1, t3 = (t >> 3) & 1;
    const int t4 = (t >> 4) & 1, t5 = (t >> 5) & 1, t6 = (t >> 6) & 1;
    const int thi = t >> 4;

    // ---- Phase A ----
    #pragma unroll
    for (int j = 0; j < 16; ++j) bf_quad(r[j]);
    #pragma unroll
    for (int m = 1; m <= 8; m <<= 1) {
        #pragma unroll
        for (int j = 0; j < 16; ++j) {
            if (!(j & m)) bf_pair(r[j], r[j | m]);
        }
    }
    const int wA = (t0 << 1) | ((t1 ^ t4) << 2) | ((t2 ^ t5) << 3)
                 | ((t3 ^ t6) << 4) | (thi << 5);
    #pragma unroll
    for (int j = 0; j < 16; ++j) {
        uint2 u;
        u.x = pk16(r[j].x, r[j].y);
        u.y = pk16(r[j].z, r[j].w);
        *reinterpret_cast<uint2*>(lds + wA + (j << 9)) = u;
    }
    __syncthreads();

    // ---- Phase B ----
    float e[8][8];
    const int wB = ((t & 15) << 5) | (thi << 9);
    int wb[8];
    #pragma unroll
    for (int j = 0; j < 8; ++j) {
        wb[j] = wB | ((j ^ (t & 7)) << 2);
        uint4 u = *reinterpret_cast<const uint4*>(lds + wb[j]);
        float2 f0 = up16(u.x), f1 = up16(u.y), f2 = up16(u.z), f3 = up16(u.w);
        e[j][0] = f0.x; e[j][1] = f0.y; e[j][2] = f1.x; e[j][3] = f1.y;
        e[j][4] = f2.x; e[j][5] = f2.y; e[j][6] = f3.x; e[j][7] = f3.y;
    }
    #pragma unroll
    for (int j = 0; j < 8; ++j) {
        #pragma unroll
        for (int q = 0; q < 4; ++q) {
            float a = e[j][q], b = e[j][q + 4];
            e[j][q] = a + b; e[j][q + 4] = a - b;
        }
    }
    #pragma unroll
    for (int m = 1; m <= 4; m <<= 1) {
        #pragma unroll
        for (int j = 0; j < 8; ++j) {
            if (!(j & m)) {
                #pragma unroll
                for (int q = 0; q < 8; ++q) {
                    float a = e[j][q], b = e[j | m][q];
                    e[j][q] = a + b; e[j | m][q] = a - b;
                }
            }
        }
    }
    #pragma unroll
    for (int j = 0; j < 8; ++j) {
        uint4 u;
        u.x = pk16(e[j][0], e[j][1]);
        u.y = pk16(e[j][2], e[j][3]);
        u.z = pk16(e[j][4], e[j][5]);
        u.w = pk16(e[j][6], e[j][7]);
        *reinterpret_cast<uint4*>(lds + wb[j]) = u;
    }
    __syncthreads();

    // ---- Phase C ----
    const int wC = (t0 << 1) | (thi << 9);
    const int tm = (t >> 1) & 7;
    #pragma unroll
    for (int k = 0; k < 16; ++k) {
        const int w = wC | (((k & 7) ^ tm) << 2) | (k << 5);
        uint2 u = *reinterpret_cast<const uint2*>(lds + w);
        float2 f0 = up16(u.x), f1 = up16(u.y);
        c[k].x = f0.x; c[k].y = f0.y; c[k].z = f1.x; c[k].w = f1.y;
    }
    #pragma unroll
    for (int m = 1; m <= 8; m <<= 1) {
        #pragma unroll
        for (int k = 0; k < 16; ++k) {
            if (!(k & m)) bf_pair(c[k], c[k | m]);
        }
    }
}

// fwd: f2v = v .* WHT2D(x), stored bf16 into first 32 KiB of each plane slot.
__global__ __launch_bounds__(256, 5) void k_fwd(const float* __restrict__ x,
                                                void* outbuf,
                                                const float* __restrict__ v) {
    __shared__ unsigned lds[8192];
    const int t = threadIdx.x;
    const int plane = blockIdx.x;
    const float4* s4 = reinterpret_cast<const float4*>(x + (size_t)plane * HW);

    float4 r[16];
    #pragma unroll
    for (int j = 0; j < 16; ++j) r[j] = s4[t + j * 256];

    float4 c[16];
    wht_ABC(r, lds, t, c);

    ushort4* dst = reinterpret_cast<ushort4*>((char*)outbuf + (size_t)plane * SLOTB);
    const int obase = (t & 15) + ((t >> 4) << 8);
    #pragma unroll
    for (int k = 0; k < 16; ++k) {
        const int o4 = obase + (k << 4);
        const float4 vv = *reinterpret_cast<const float4*>(v + (o4 << 2));
        ushort4 u;
        u.x = f2bf(c[k].x * vv.x);
        u.y = f2bf(c[k].y * vv.y);
        u.z = f2bf(c[k].z * vv.z);
        u.w = f2bf(c[k].w * vv.w);
        dst[o4] = u;
    }
}

// inv: y = WHT2D(f6)/16384 + x, reads bf16 f6 from slot head, writes fp32 y.
__global__ __launch_bounds__(256, 5) void k_inv(void* outbuf,
                                                const float* __restrict__ x) {
    __shared__ unsigned lds[8192];
    const int t = threadIdx.x;
    const int plane = blockIdx.x;
    const float sc = 1.0f / 16384.0f;
    const ushort4* src =
        reinterpret_cast<const ushort4*>((const char*)outbuf + (size_t)plane * SLOTB);

    float4 r[16];
    #pragma unroll
    for (int j = 0; j < 16; ++j) {
        ushort4 u = src[t + j * 256];
        r[j].x = bf2f(u.x) * sc; r[j].y = bf2f(u.y) * sc;
        r[j].z = bf2f(u.z) * sc; r[j].w = bf2f(u.w) * sc;
    }

    float4 c[16];
    wht_ABC(r, lds, t, c);

    float* dst = reinterpret_cast<float*>((char*)outbuf + (size_t)plane * SLOTB);
    const float* xr = x + (size_t)plane * HW;
    const int obase = (t & 15) + ((t >> 4) << 8);
    #pragma unroll
    for (int k = 0; k < 16; ++k) {
        const int o4 = obase + (k << 4);
        float4 xv = *reinterpret_cast<const float4*>(xr + (o4 << 2));
        float4 o;
        o.x = c[k].x + xv.x; o.y = c[k].y + xv.y;
        o.z = c[k].z + xv.z; o.w = c[k].w + xv.w;
        *reinterpret_cast<float4*>(dst + (o4 << 2)) = o;
    }
}

// ---------------------------------------------------------------------------
// Channel mix via bf16 MFMA (R8-exact; plain cached loads/stores).
// ---------------------------------------------------------------------------
__global__ __launch_bounds__(256, 5) void k_mix_mfma(void* buf,
                                                     const float* __restrict__ W,
                                                     const float* __restrict__ T) {
    __shared__ float Xs[64 * 128];  // 32 KiB
    const int t = threadIdx.x;
    const int l = t & 63, w = t >> 6;
    const int b  = blockIdx.x >> 7;
    const int p0 = (blockIdx.x & 127) << 7;

    bf16x8 A[4][2];
    {
        const int row = l & 15;
        const int kc  = (l >> 4) * 8;
        #pragma unroll
        for (int mt = 0; mt < 4; ++mt) {
            const float* wr = W + (mt * 16 + row) * 64 + kc;
            #pragma unroll
            for (int ks = 0; ks < 2; ++ks) {
                float4 w0 = *reinterpret_cast<const float4*>(wr + ks * 32);
                float4 w1 = *reinterpret_cast<const float4*>(wr + ks * 32 + 4);
                bf16x8 a;
                a[0] = (__bf16)w0.x; a[1] = (__bf16)w0.y;
                a[2] = (__bf16)w0.z; a[3] = (__bf16)w0.w;
                a[4] = (__bf16)w1.x; a[5] = (__bf16)w1.y;
                a[6] = (__bf16)w1.z; a[7] = (__bf16)w1.w;
                A[mt][ks] = a;
            }
        }
    }

    #pragma unroll
    for (int i = 0; i < 8; ++i) {
        const int d  = i * 1024 + t * 4;
        const int cc = d >> 7;
        const int pq = d & 127;
        const ushort4* src = reinterpret_cast<const ushort4*>(
            (const char*)buf + (size_t)(b * 64 + cc) * SLOTB);
        ushort4 u = src[(p0 + pq) >> 2];
        float4 r;
        r.x = bf2f(u.x); r.y = bf2f(u.y); r.z = bf2f(u.z); r.w = bf2f(u.w);
        const int gc = (cc >> 3) & 3;
        *reinterpret_cast<float4*>(Xs + cc * 128 + (pq ^ (gc << 4))) = r;
    }
    __syncthreads();

    f32x4 acc[4][2] = {};
    const int n0 = w * 32;
    const int g  = l >> 4;
    #pragma unroll
    for (int nt = 0; nt < 2; ++nt) {
        const int pl = n0 + nt * 16 + (l & 15);
        #pragma unroll
        for (int ks = 0; ks < 2; ++ks) {
            const float* col = Xs + (ks * 32 + g * 8) * 128 + (pl ^ (g << 4));
            bf16x8 bb;
            #pragma unroll
            for (int j = 0; j < 8; ++j) bb[j] = (__bf16)col[j * 128];
            #pragma unroll
            for (int mt = 0; mt < 4; ++mt)
                acc[mt][nt] = __builtin_amdgcn_mfma_f32_16x16x32_bf16(
                    A[mt][ks], bb, acc[mt][nt], 0, 0, 0);
        }
    }

    #pragma unroll
    for (int nt = 0; nt < 2; ++nt) {
        const int p  = p0 + n0 + nt * 16 + (l & 15);
        const float Tp = fmaxf(T[p], 0.0f);
        #pragma unroll
        for (int mt = 0; mt < 4; ++mt) {
            unsigned short* orow = reinterpret_cast<unsigned short*>(
                (char*)buf + (size_t)(b * 64 + mt * 16 + g * 4) * SLOTB);
            #pragma unroll
            for (int r = 0; r < 4; ++r) {
                float val = acc[mt][nt][r];
                float mag = fmaxf(fabsf(val) - Tp, 0.0f);
                reinterpret_cast<unsigned short*>(
                    (char*)orow + (size_t)r * SLOTB)[p] = f2bf(copysignf(mag, val));
            }
        }
    }
}

extern "C" void kernel_launch(void* const* d_in, const int* in_sizes, int n_in,
                              void* d_out, int out_size, void* d_ws, size_t ws_size,
                              hipStream_t stream) {
    const float* x = (const float*)d_in[0];
    const float* W = (const float*)d_in[1];
    const float* v = (const float*)d_in[2];
    const float* T = (const float*)d_in[3];

    // f2v = v .* WHT2D(x) -> bf16, slot heads of d_out
    k_fwd<<<NPLANE, 256, 0, stream>>>(x, d_out, v);
    // f6 = soft_threshold(W @ f2v, T) -> bf16, in place
    k_mix_mfma<<<32 * 128, 256, 0, stream>>>(d_out, W, T);
    // y = WHT2D(f6)/16384 + x -> fp32, full slots of d_out
    k_inv<<<NPLANE, 256, 0, stream>>>(d_out, x);
}

// Round 15
// 163.377 us; speedup vs baseline: 1.4910x; 1.4910x over previous
//
#include <hip/hip_runtime.h>
#include <math.h>

// Problem constants: B=32, C=64, H=128, W=128
#define HW 16384         // plane elements
#define NPLANE 2048      // B*C planes
#define SLOTB 65536ull   // bytes per plane slot in d_out (fp32 plane)
// Slot layout between k_fwd and k_inv:
//   bytes 0..32767   : f2v (then f6) as bf16
//   bytes 32768..65535: x stashed as fp16 pairs (linear float4 order)
// k_inv overwrites the whole slot with fp32 y.

typedef __fp16 f16x2 __attribute__((ext_vector_type(2)));
typedef __bf16 bf16x8 __attribute__((ext_vector_type(8)));
typedef float  f32x4  __attribute__((ext_vector_type(4)));

__device__ __forceinline__ unsigned pk16(float a, float b) {
    f16x2 h = __builtin_amdgcn_cvt_pkrtz(a, b);
    return __builtin_bit_cast(unsigned, h);
}
__device__ __forceinline__ float2 up16(unsigned u) {
    f16x2 h = __builtin_bit_cast(f16x2, u);
    return make_float2((float)h[0], (float)h[1]);
}
__device__ __forceinline__ float bf2f(unsigned short s) {
    unsigned u = (unsigned)s << 16;
    return __builtin_bit_cast(float, u);
}
__device__ __forceinline__ unsigned short f2bf(float f) {
    __bf16 h = (__bf16)f;
    return __builtin_bit_cast(unsigned short, h);
}

__device__ __forceinline__ void bf_quad(float4& a) {
    float s0 = a.x + a.y, d0 = a.x - a.y;
    float s1 = a.z + a.w, d1 = a.z - a.w;
    a.x = s0 + s1; a.y = d0 + d1; a.z = s0 - s1; a.w = d0 - d1;
}
__device__ __forceinline__ void bf_pair(float4& a, float4& b) {
    float4 s, d;
    s.x = a.x + b.x; s.y = a.y + b.y; s.z = a.z + b.z; s.w = a.w + b.w;
    d.x = a.x - b.x; d.y = a.y - b.y; d.z = a.z - b.z; d.w = a.w - b.w;
    a = s; b = d;
}

// ---------------------------------------------------------------------------
// 14-stage WHT over one 16384 plane. 256 threads x 64 elems. (verified R8)
// ---------------------------------------------------------------------------
__device__ __forceinline__ void wht_ABC(float4 (&r)[16], unsigned* lds, int t,
                                        float4 (&c)[16]) {
    const int t0 = t & 1, t1 = (t >> 1) & 1, t2 = (t >> 2) & 1, t3 = (t >> 3) & 1;
    const int t4 = (t >> 4) & 1, t5 = (t >> 5) & 1, t6 = (t >> 6) & 1;
    const int thi = t >> 4;

    // ---- Phase A ----
    #pragma unroll
    for (int j = 0; j < 16; ++j) bf_quad(r[j]);
    #pragma unroll
    for (int m = 1; m <= 8; m <<= 1) {
        #pragma unroll
        for (int j = 0; j < 16; ++j) {
            if (!(j & m)) bf_pair(r[j], r[j | m]);
        }
    }
    const int wA = (t0 << 1) | ((t1 ^ t4) << 2) | ((t2 ^ t5) << 3)
                 | ((t3 ^ t6) << 4) | (thi << 5);
    #pragma unroll
    for (int j = 0; j < 16; ++j) {
        uint2 u;
        u.x = pk16(r[j].x, r[j].y);
        u.y = pk16(r[j].z, r[j].w);
        *reinterpret_cast<uint2*>(lds + wA + (j << 9)) = u;
    }
    __syncthreads();

    // ---- Phase B ----
    float e[8][8];
    const int wB = ((t & 15) << 5) | (thi << 9);
    int wb[8];
    #pragma unroll
    for (int j = 0; j < 8; ++j) {
        wb[j] = wB | ((j ^ (t & 7)) << 2);
        uint4 u = *reinterpret_cast<const uint4*>(lds + wb[j]);
        float2 f0 = up16(u.x), f1 = up16(u.y), f2 = up16(u.z), f3 = up16(u.w);
        e[j][0] = f0.x; e[j][1] = f0.y; e[j][2] = f1.x; e[j][3] = f1.y;
        e[j][4] = f2.x; e[j][5] = f2.y; e[j][6] = f3.x; e[j][7] = f3.y;
    }
    #pragma unroll
    for (int j = 0; j < 8; ++j) {
        #pragma unroll
        for (int q = 0; q < 4; ++q) {
            float a = e[j][q], b = e[j][q + 4];
            e[j][q] = a + b; e[j][q + 4] = a - b;
        }
    }
    #pragma unroll
    for (int m = 1; m <= 4; m <<= 1) {
        #pragma unroll
        for (int j = 0; j < 8; ++j) {
            if (!(j & m)) {
                #pragma unroll
                for (int q = 0; q < 8; ++q) {
                    float a = e[j][q], b = e[j | m][q];
                    e[j][q] = a + b; e[j | m][q] = a - b;
                }
            }
        }
    }
    #pragma unroll
    for (int j = 0; j < 8; ++j) {
        uint4 u;
        u.x = pk16(e[j][0], e[j][1]);
        u.y = pk16(e[j][2], e[j][3]);
        u.z = pk16(e[j][4], e[j][5]);
        u.w = pk16(e[j][6], e[j][7]);
        *reinterpret_cast<uint4*>(lds + wb[j]) = u;
    }
    __syncthreads();

    // ---- Phase C ----
    const int wC = (t0 << 1) | (thi << 9);
    const int tm = (t >> 1) & 7;
    #pragma unroll
    for (int k = 0; k < 16; ++k) {
        const int w = wC | (((k & 7) ^ tm) << 2) | (k << 5);
        uint2 u = *reinterpret_cast<const uint2*>(lds + w);
        float2 f0 = up16(u.x), f1 = up16(u.y);
        c[k].x = f0.x; c[k].y = f0.y; c[k].z = f1.x; c[k].w = f1.y;
    }
    #pragma unroll
    for (int m = 1; m <= 8; m <<= 1) {
        #pragma unroll
        for (int k = 0; k < 16; ++k) {
            if (!(k & m)) bf_pair(c[k], c[k | m]);
        }
    }
}

// fwd: f2v = v .* WHT2D(x) -> bf16 slot head; also stash x as fp16 in slot
// tail (linear float4 order) so k_inv's residual read is L3-hot.
__global__ __launch_bounds__(256, 4) void k_fwd(const float* __restrict__ x,
                                                void* outbuf,
                                                const float* __restrict__ v) {
    __shared__ unsigned lds[8192];
    const int t = threadIdx.x;
    const int plane = blockIdx.x;
    const float4* s4 = reinterpret_cast<const float4*>(x + (size_t)plane * HW);

    float4 r[16];
    #pragma unroll
    for (int j = 0; j < 16; ++j) r[j] = s4[t + j * 256];

    // Stash x (pre-WHT values) as fp16 pairs into the slot tail.
    uint2* xt = reinterpret_cast<uint2*>(
        (char*)outbuf + (size_t)plane * SLOTB + 32768);
    #pragma unroll
    for (int j = 0; j < 16; ++j) {
        uint2 u;
        u.x = pk16(r[j].x, r[j].y);
        u.y = pk16(r[j].z, r[j].w);
        xt[t + j * 256] = u;
    }

    float4 c[16];
    wht_ABC(r, lds, t, c);

    ushort4* dst = reinterpret_cast<ushort4*>((char*)outbuf + (size_t)plane * SLOTB);
    const int obase = (t & 15) + ((t >> 4) << 8);
    #pragma unroll
    for (int k = 0; k < 16; ++k) {
        const int o4 = obase + (k << 4);
        const float4 vv = *reinterpret_cast<const float4*>(v + (o4 << 2));
        ushort4 u;
        u.x = f2bf(c[k].x * vv.x);
        u.y = f2bf(c[k].y * vv.y);
        u.z = f2bf(c[k].z * vv.z);
        u.w = f2bf(c[k].w * vv.w);
        dst[o4] = u;
    }
}

// inv: y = WHT2D(f6)/16384 + x. f6 from slot head, x from slot tail (fp16,
// L3-hot). Epilogue: read all x, barrier (cross-thread read-before-write
// ordering), then overwrite the slot with fp32 y.
__global__ __launch_bounds__(256, 4) void k_inv(void* outbuf) {
    __shared__ unsigned lds[8192];
    const int t = threadIdx.x;
    const int plane = blockIdx.x;
    const float sc = 1.0f / 16384.0f;
    const ushort4* src =
        reinterpret_cast<const ushort4*>((const char*)outbuf + (size_t)plane * SLOTB);

    float4 r[16];
    #pragma unroll
    for (int j = 0; j < 16; ++j) {
        ushort4 u = src[t + j * 256];
        r[j].x = bf2f(u.x) * sc; r[j].y = bf2f(u.y) * sc;
        r[j].z = bf2f(u.z) * sc; r[j].w = bf2f(u.w) * sc;
    }

    float4 c[16];
    wht_ABC(r, lds, t, c);

    const uint2* xt = reinterpret_cast<const uint2*>(
        (const char*)outbuf + (size_t)plane * SLOTB + 32768);
    const int obase = (t & 15) + ((t >> 4) << 8);
    uint2 xp[16];
    #pragma unroll
    for (int k = 0; k < 16; ++k) xp[k] = xt[obase + (k << 4)];
    __syncthreads();  // all tail reads complete before any slot overwrite

    float* dst = reinterpret_cast<float*>((char*)outbuf + (size_t)plane * SLOTB);
    #pragma unroll
    for (int k = 0; k < 16; ++k) {
        const int o4 = obase + (k << 4);
        float2 lo = up16(xp[k].x), hi = up16(xp[k].y);
        float4 o;
        o.x = c[k].x + lo.x; o.y = c[k].y + lo.y;
        o.z = c[k].z + hi.x; o.w = c[k].w + hi.y;
        *reinterpret_cast<float4*>(dst + (o4 << 2)) = o;
    }
}

// ---------------------------------------------------------------------------
// Channel mix via bf16 MFMA (R8-exact). Touches slot heads only.
// ---------------------------------------------------------------------------
__global__ __launch_bounds__(256, 4) void k_mix_mfma(void* buf,
                                                     const float* __restrict__ W,
                                                     const float* __restrict__ T) {
    __shared__ float Xs[64 * 128];  // 32 KiB
    const int t = threadIdx.x;
    const int l = t & 63, w = t >> 6;
    const int b  = blockIdx.x >> 7;
    const int p0 = (blockIdx.x & 127) << 7;

    bf16x8 A[4][2];
    {
        const int row = l & 15;
        const int kc  = (l >> 4) * 8;
        #pragma unroll
        for (int mt = 0; mt < 4; ++mt) {
            const float* wr = W + (mt * 16 + row) * 64 + kc;
            #pragma unroll
            for (int ks = 0; ks < 2; ++ks) {
                float4 w0 = *reinterpret_cast<const float4*>(wr + ks * 32);
                float4 w1 = *reinterpret_cast<const float4*>(wr + ks * 32 + 4);
                bf16x8 a;
                a[0] = (__bf16)w0.x; a[1] = (__bf16)w0.y;
                a[2] = (__bf16)w0.z; a[3] = (__bf16)w0.w;
                a[4] = (__bf16)w1.x; a[5] = (__bf16)w1.y;
                a[6] = (__bf16)w1.z; a[7] = (__bf16)w1.w;
                A[mt][ks] = a;
            }
        }
    }

    #pragma unroll
    for (int i = 0; i < 8; ++i) {
        const int d  = i * 1024 + t * 4;
        const int cc = d >> 7;
        const int pq = d & 127;
        const ushort4* src = reinterpret_cast<const ushort4*>(
            (const char*)buf + (size_t)(b * 64 + cc) * SLOTB);
        ushort4 u = src[(p0 + pq) >> 2];
        float4 r;
        r.x = bf2f(u.x); r.y = bf2f(u.y); r.z = bf2f(u.z); r.w = bf2f(u.w);
        const int gc = (cc >> 3) & 3;
        *reinterpret_cast<float4*>(Xs + cc * 128 + (pq ^ (gc << 4))) = r;
    }
    __syncthreads();

    f32x4 acc[4][2] = {};
    const int n0 = w * 32;
    const int g  = l >> 4;
    #pragma unroll
    for (int nt = 0; nt < 2; ++nt) {
        const int pl = n0 + nt * 16 + (l & 15);
        #pragma unroll
        for (int ks = 0; ks < 2; ++ks) {
            const float* col = Xs + (ks * 32 + g * 8) * 128 + (pl ^ (g << 4));
            bf16x8 bb;
            #pragma unroll
            for (int j = 0; j < 8; ++j) bb[j] = (__bf16)col[j * 128];
            #pragma unroll
            for (int mt = 0; mt < 4; ++mt)
                acc[mt][nt] = __builtin_amdgcn_mfma_f32_16x16x32_bf16(
                    A[mt][ks], bb, acc[mt][nt], 0, 0, 0);
        }
    }

    #pragma unroll
    for (int nt = 0; nt < 2; ++nt) {
        const int p  = p0 + n0 + nt * 16 + (l & 15);
        const float Tp = fmaxf(T[p], 0.0f);
        #pragma unroll
        for (int mt = 0; mt < 4; ++mt) {
            unsigned short* orow = reinterpret_cast<unsigned short*>(
                (char*)buf + (size_t)(b * 64 + mt * 16 + g * 4) * SLOTB);
            #pragma unroll
            for (int r = 0; r < 4; ++r) {
                float val = acc[mt][nt][r];
                float mag = fmaxf(fabsf(val) - Tp, 0.0f);
                reinterpret_cast<unsigned short*>(
                    (char*)orow + (size_t)r * SLOTB)[p] = f2bf(copysignf(mag, val));
            }
        }
    }
}

extern "C" void kernel_launch(void* const* d_in, const int* in_sizes, int n_in,
                              void* d_out, int out_size, void* d_ws, size_t ws_size,
                              hipStream_t stream) {
    const float* x = (const float*)d_in[0];
    const float* W = (const float*)d_in[1];
    const float* v = (const float*)d_in[2];
    const float* T = (const float*)d_in[3];

    // f2v = v .* WHT2D(x) -> bf16 slot heads; x -> fp16 slot tails
    k_fwd<<<NPLANE, 256, 0, stream>>>(x, d_out, v);
    // f6 = soft_threshold(W @ f2v, T) -> bf16, in place (heads only)
    k_mix_mfma<<<32 * 128, 256, 0, stream>>>(d_out, W, T);
    // y = WHT2D(f6)/16384 + x -> fp32, full slots of d_out
    k_inv<<<NPLANE, 256, 0, stream>>>(d_out);
}

// Round 16
// 149.851 us; speedup vs baseline: 1.6255x; 1.0903x over previous
//
#include <hip/hip_runtime.h>
#include <math.h>

// Problem constants: B=32, C=64, H=128, W=128
#define HW 16384         // plane elements
#define NPLANE 2048      // B*C planes
#define SLOTB 65536ull   // bytes per plane slot in d_out (fp32 plane)

typedef __fp16 f16x2 __attribute__((ext_vector_type(2)));
typedef __bf16 bf16x8 __attribute__((ext_vector_type(8)));
typedef float  f32x4  __attribute__((ext_vector_type(4)));

__device__ __forceinline__ unsigned pk16(float a, float b) {
    f16x2 h = __builtin_amdgcn_cvt_pkrtz(a, b);
    return __builtin_bit_cast(unsigned, h);
}
__device__ __forceinline__ float2 up16(unsigned u) {
    f16x2 h = __builtin_bit_cast(f16x2, u);
    return make_float2((float)h[0], (float)h[1]);
}
__device__ __forceinline__ float bf2f(unsigned short s) {
    unsigned u = (unsigned)s << 16;
    return __builtin_bit_cast(float, u);
}
__device__ __forceinline__ unsigned short f2bf(float f) {
    __bf16 h = (__bf16)f;
    return __builtin_bit_cast(unsigned short, h);
}

__device__ __forceinline__ void bf_quad(float4& a) {
    float s0 = a.x + a.y, d0 = a.x - a.y;
    float s1 = a.z + a.w, d1 = a.z - a.w;
    a.x = s0 + s1; a.y = d0 + d1; a.z = s0 - s1; a.w = d0 - d1;
}
__device__ __forceinline__ void bf_pair(float4& a, float4& b) {
    float4 s, d;
    s.x = a.x + b.x; s.y = a.y + b.y; s.z = a.z + b.z; s.w = a.w + b.w;
    d.x = a.x - b.x; d.y = a.y - b.y; d.z = a.z - b.z; d.w = a.w - b.w;
    a = s; b = d;
}

// ---------------------------------------------------------------------------
// 14-stage WHT over one 16384 plane. 256 threads x 64 elems. (verified R8)
// ---------------------------------------------------------------------------
__device__ __forceinline__ void wht_ABC(float4 (&r)[16], unsigned* lds, int t,
                                        float4 (&c)[16]) {
    const int t0 = t & 1, t1 = (t >> 1) & 1, t2 = (t >> 2) & 1, t3 = (t >> 3) & 1;
    const int t4 = (t >> 4) & 1, t5 = (t >> 5) & 1, t6 = (t >> 6) & 1;
    const int thi = t >> 4;

    // ---- Phase A ----
    #pragma unroll
    for (int j = 0; j < 16; ++j) bf_quad(r[j]);
    #pragma unroll
    for (int m = 1; m <= 8; m <<= 1) {
        #pragma unroll
        for (int j = 0; j < 16; ++j) {
            if (!(j & m)) bf_pair(r[j], r[j | m]);
        }
    }
    const int wA = (t0 << 1) | ((t1 ^ t4) << 2) | ((t2 ^ t5) << 3)
                 | ((t3 ^ t6) << 4) | (thi << 5);
    #pragma unroll
    for (int j = 0; j < 16; ++j) {
        uint2 u;
        u.x = pk16(r[j].x, r[j].y);
        u.y = pk16(r[j].z, r[j].w);
        *reinterpret_cast<uint2*>(lds + wA + (j << 9)) = u;
    }
    __syncthreads();

    // ---- Phase B ----
    float e[8][8];
    const int wB = ((t & 15) << 5) | (thi << 9);
    int wb[8];
    #pragma unroll
    for (int j = 0; j < 8; ++j) {
        wb[j] = wB | ((j ^ (t & 7)) << 2);
        uint4 u = *reinterpret_cast<const uint4*>(lds + wb[j]);
        float2 f0 = up16(u.x), f1 = up16(u.y), f2 = up16(u.z), f3 = up16(u.w);
        e[j][0] = f0.x; e[j][1] = f0.y; e[j][2] = f1.x; e[j][3] = f1.y;
        e[j][4] = f2.x; e[j][5] = f2.y; e[j][6] = f3.x; e[j][7] = f3.y;
    }
    #pragma unroll
    for (int j = 0; j < 8; ++j) {
        #pragma unroll
        for (int q = 0; q < 4; ++q) {
            float a = e[j][q], b = e[j][q + 4];
            e[j][q] = a + b; e[j][q + 4] = a - b;
        }
    }
    #pragma unroll
    for (int m = 1; m <= 4; m <<= 1) {
        #pragma unroll
        for (int j = 0; j < 8; ++j) {
            if (!(j & m)) {
                #pragma unroll
                for (int q = 0; q < 8; ++q) {
                    float a = e[j][q], b = e[j | m][q];
                    e[j][q] = a + b; e[j | m][q] = a - b;
                }
            }
        }
    }
    #pragma unroll
    for (int j = 0; j < 8; ++j) {
        uint4 u;
        u.x = pk16(e[j][0], e[j][1]);
        u.y = pk16(e[j][2], e[j][3]);
        u.z = pk16(e[j][4], e[j][5]);
        u.w = pk16(e[j][6], e[j][7]);
        *reinterpret_cast<uint4*>(lds + wb[j]) = u;
    }
    __syncthreads();

    // ---- Phase C ----
    const int wC = (t0 << 1) | (thi << 9);
    const int tm = (t >> 1) & 7;
    #pragma unroll
    for (int k = 0; k < 16; ++k) {
        const int w = wC | (((k & 7) ^ tm) << 2) | (k << 5);
        uint2 u = *reinterpret_cast<const uint2*>(lds + w);
        float2 f0 = up16(u.x), f1 = up16(u.y);
        c[k].x = f0.x; c[k].y = f0.y; c[k].z = f1.x; c[k].w = f1.y;
    }
    #pragma unroll
    for (int m = 1; m <= 8; m <<= 1) {
        #pragma unroll
        for (int k = 0; k < 16; ++k) {
            if (!(k & m)) bf_pair(c[k], c[k | m]);
        }
    }
}

// fwd: f2v = v .* WHT2D(x), stored bf16 into first 32 KiB of each plane slot.
__global__ __launch_bounds__(256, 4) void k_fwd(const float* __restrict__ x,
                                                void* outbuf,
                                                const float* __restrict__ v) {
    __shared__ unsigned lds[8192];
    const int t = threadIdx.x;
    const int plane = blockIdx.x;
    const float4* s4 = reinterpret_cast<const float4*>(x + (size_t)plane * HW);

    float4 r[16];
    #pragma unroll
    for (int j = 0; j < 16; ++j) r[j] = s4[t + j * 256];

    float4 c[16];
    wht_ABC(r, lds, t, c);

    ushort4* dst = reinterpret_cast<ushort4*>((char*)outbuf + (size_t)plane * SLOTB);
    const int obase = (t & 15) + ((t >> 4) << 8);
    #pragma unroll
    for (int k = 0; k < 16; ++k) {
        const int o4 = obase + (k << 4);
        const float4 vv = *reinterpret_cast<const float4*>(v + (o4 << 2));
        ushort4 u;
        u.x = f2bf(c[k].x * vv.x);
        u.y = f2bf(c[k].y * vv.y);
        u.z = f2bf(c[k].z * vv.z);
        u.w = f2bf(c[k].w * vv.w);
        dst[o4] = u;
    }
}

// inv: y = WHT2D(f6)/16384 + x, reads bf16 f6 from slot head, writes fp32 y.
// Planes consumed in REVERSE order: fwd/mix touched slots ascending, so the
// tail of x and the slots are the L3-freshest — start there.
__global__ __launch_bounds__(256, 4) void k_inv(void* outbuf,
                                                const float* __restrict__ x) {
    __shared__ unsigned lds[8192];
    const int t = threadIdx.x;
    const int plane = NPLANE - 1 - blockIdx.x;
    const float sc = 1.0f / 16384.0f;
    const ushort4* src =
        reinterpret_cast<const ushort4*>((const char*)outbuf + (size_t)plane * SLOTB);

    float4 r[16];
    #pragma unroll
    for (int j = 0; j < 16; ++j) {
        ushort4 u = src[t + j * 256];
        r[j].x = bf2f(u.x) * sc; r[j].y = bf2f(u.y) * sc;
        r[j].z = bf2f(u.z) * sc; r[j].w = bf2f(u.w) * sc;
    }

    float4 c[16];
    wht_ABC(r, lds, t, c);

    float* dst = reinterpret_cast<float*>((char*)outbuf + (size_t)plane * SLOTB);
    const float* xr = x + (size_t)plane * HW;
    const int obase = (t & 15) + ((t >> 4) << 8);
    #pragma unroll
    for (int k = 0; k < 16; ++k) {
        const int o4 = obase + (k << 4);
        float4 xv = *reinterpret_cast<const float4*>(xr + (o4 << 2));
        float4 o;
        o.x = c[k].x + xv.x; o.y = c[k].y + xv.y;
        o.z = c[k].z + xv.z; o.w = c[k].w + xv.w;
        *reinterpret_cast<float4*>(dst + (o4 << 2)) = o;
    }
}

// ---------------------------------------------------------------------------
// Channel mix via bf16 MFMA (R8-exact).
// ---------------------------------------------------------------------------
__global__ __launch_bounds__(256, 4) void k_mix_mfma(void* buf,
                                                     const float* __restrict__ W,
                                                     const float* __restrict__ T) {
    __shared__ float Xs[64 * 128];  // 32 KiB
    const int t = threadIdx.x;
    const int l = t & 63, w = t >> 6;
    const int b  = blockIdx.x >> 7;
    const int p0 = (blockIdx.x & 127) << 7;

    bf16x8 A[4][2];
    {
        const int row = l & 15;
        const int kc  = (l >> 4) * 8;
        #pragma unroll
        for (int mt = 0; mt < 4; ++mt) {
            const float* wr = W + (mt * 16 + row) * 64 + kc;
            #pragma unroll
            for (int ks = 0; ks < 2; ++ks) {
                float4 w0 = *reinterpret_cast<const float4*>(wr + ks * 32);
                float4 w1 = *reinterpret_cast<const float4*>(wr + ks * 32 + 4);
                bf16x8 a;
                a[0] = (__bf16)w0.x; a[1] = (__bf16)w0.y;
                a[2] = (__bf16)w0.z; a[3] = (__bf16)w0.w;
                a[4] = (__bf16)w1.x; a[5] = (__bf16)w1.y;
                a[6] = (__bf16)w1.z; a[7] = (__bf16)w1.w;
                A[mt][ks] = a;
            }
        }
    }

    #pragma unroll
    for (int i = 0; i < 8; ++i) {
        const int d  = i * 1024 + t * 4;
        const int cc = d >> 7;
        const int pq = d & 127;
        const ushort4* src = reinterpret_cast<const ushort4*>(
            (const char*)buf + (size_t)(b * 64 + cc) * SLOTB);
        ushort4 u = src[(p0 + pq) >> 2];
        float4 r;
        r.x = bf2f(u.x); r.y = bf2f(u.y); r.z = bf2f(u.z); r.w = bf2f(u.w);
        const int gc = (cc >> 3) & 3;
        *reinterpret_cast<float4*>(Xs + cc * 128 + (pq ^ (gc << 4))) = r;
    }
    __syncthreads();

    f32x4 acc[4][2] = {};
    const int n0 = w * 32;
    const int g  = l >> 4;
    #pragma unroll
    for (int nt = 0; nt < 2; ++nt) {
        const int pl = n0 + nt * 16 + (l & 15);
        #pragma unroll
        for (int ks = 0; ks < 2; ++ks) {
            const float* col = Xs + (ks * 32 + g * 8) * 128 + (pl ^ (g << 4));
            bf16x8 bb;
            #pragma unroll
            for (int j = 0; j < 8; ++j) bb[j] = (__bf16)col[j * 128];
            #pragma unroll
            for (int mt = 0; mt < 4; ++mt)
                acc[mt][nt] = __builtin_amdgcn_mfma_f32_16x16x32_bf16(
                    A[mt][ks], bb, acc[mt][nt], 0, 0, 0);
        }
    }

    #pragma unroll
    for (int nt = 0; nt < 2; ++nt) {
        const int p  = p0 + n0 + nt * 16 + (l & 15);
        const float Tp = fmaxf(T[p], 0.0f);
        #pragma unroll
        for (int mt = 0; mt < 4; ++mt) {
            unsigned short* orow = reinterpret_cast<unsigned short*>(
                (char*)buf + (size_t)(b * 64 + mt * 16 + g * 4) * SLOTB);
            #pragma unroll
            for (int r = 0; r < 4; ++r) {
                float val = acc[mt][nt][r];
                float mag = fmaxf(fabsf(val) - Tp, 0.0f);
                reinterpret_cast<unsigned short*>(
                    (char*)orow + (size_t)r * SLOTB)[p] = f2bf(copysignf(mag, val));
            }
        }
    }
}

extern "C" void kernel_launch(void* const* d_in, const int* in_sizes, int n_in,
                              void* d_out, int out_size, void* d_ws, size_t ws_size,
                              hipStream_t stream) {
    const float* x = (const float*)d_in[0];
    const float* W = (const float*)d_in[1];
    const float* v = (const float*)d_in[2];
    const float* T = (const float*)d_in[3];

    // f2v = v .* WHT2D(x) -> bf16, slot heads of d_out
    k_fwd<<<NPLANE, 256, 0, stream>>>(x, d_out, v);
    // f6 = soft_threshold(W @ f2v, T) -> bf16, in place
    k_mix_mfma<<<32 * 128, 256, 0, stream>>>(d_out, W, T);
    // y = WHT2D(f6)/16384 + x -> fp32, full slots of d_out
    k_inv<<<NPLANE, 256, 0, stream>>>(d_out, x);
}